// Round 6
// baseline (729.440 us; speedup 1.0000x reference)
//
#include <hip/hip_runtime.h>
#include <math.h>

#define B_    256
#define NCH   32
#define T_    2000
#define NTF   4
#define NSF   40
#define NSUB  20
#define TK    25
#define NCLS  4
#define NTAN  210
#define NPAIR 820
#define ACC_STRIDE 860
#define TILE_T 250
#define NTILE  8
#define PL     12

#define ACC_FLOATS (B_*ACC_STRIDE)
#define W2T_OFF ACC_FLOATS                    // 5120 floats, [s][c][f]
#define W1T_OFF (ACC_FLOATS + NSF*NTF*NCH)    // 100 floats,  [k][f]

#define H2_TSTR 40          // h2[t][s]: 256 rows x 40, t-major (thread-private RMW)
#define XA_OFF  10240       // xsA[280][4] channels 8g..8g+3
#define XB_OFF  11360       // xsB[280][4] channels 8g+4..8g+7
#define LDS_DW  12480       // 49.9 KB -> 3 blocks/CU

typedef float v2f __attribute__((ext_vector_type(2)));

__device__ __forceinline__ v2f fma2(v2f a, v2f b, v2f c) {
#if __has_builtin(__builtin_elementwise_fma)
    return __builtin_elementwise_fma(a, b, c);
#else
    v2f r; r.x = fmaf(a.x, b.x, c.x); r.y = fmaf(a.y, b.y, c.y); return r;
#endif
}

__device__ __forceinline__ int pack_ut(int f, int g) {
    return f*NSF - (f*(f-1))/2 + (g - f);
}

// ---------------- K0: weight transpose ----------------
__global__ void prep_kernel(const float* __restrict__ conv1_w,
                            const float* __restrict__ conv2_w,
                            float* __restrict__ ws) {
    int tid = threadIdx.x;
    float* w2t = ws + W2T_OFF;
    float* w1t = ws + W1T_OFF;
    for (int i = tid; i < NSF*NTF*NCH; i += 256) {
        int f  = i & 3;
        int sc = i >> 2;
        int c  = sc & 31;
        int s  = sc >> 5;
        w2t[i] = conv2_w[(s*NTF + f)*NCH + c];
    }
    for (int i = tid; i < NTF*TK; i += 256) {
        int f = i & 3;
        int k = i >> 2;
        w1t[i] = conv1_w[f*TK + k];
    }
}

// ---------------- K1: fused conv1+conv2+gram, h2 in LDS (no big register arrays) ----------------
__global__ __launch_bounds__(256, 3)
void conv_gram_kernel(const float* __restrict__ x,
                      const float* __restrict__ conv1_b,
                      const float* __restrict__ conv2_b,
                      const float* __restrict__ wts,
                      float* __restrict__ acc)
{
    __shared__ float lds[LDS_DW];

    const int tid  = threadIdx.x;
    const int b    = blockIdx.x >> 3;
    const int tile = blockIdx.x & 7;
    const int t0   = tile * TILE_T;
    const bool tvalid = (tid < TILE_T);

    const float* xb = x + (size_t)b*NCH*T_;
    const float4* w1t = (const float4*)(wts + W1T_OFF);
    const float4* w2t = (const float4*)(wts + W2T_OFF);

    const float b1_0 = conv1_b[0], b1_1 = conv1_b[1], b1_2 = conv1_b[2], b1_3 = conv1_b[3];

    float* h2row = &lds[tid * H2_TSTR];

    #pragma clang loop unroll(disable)
    for (int g = 0; g < 4; ++g) {
        __syncthreads();   // previous g's conv1 reads of xs done
        // ---- stage channels 8g..8g+7 into xsA/xsB (stride 4, b128-friendly) ----
        for (int li = tid; li < 8*280; li += 256) {
            int cp = li / 280;
            int i  = li - cp*280;
            int tg = t0 + i - PL;
            tg = (tg < 0) ? -tg : tg;
            tg = (tg >= T_) ? (2*T_ - 2 - tg) : tg;
            int base = (cp < 4) ? XA_OFF : XB_OFF;
            lds[base + i*4 + (cp & 3)] = xb[(8*g + cp)*T_ + tg];
        }
        __syncthreads();

        // ---- conv1: h1 for 8 channels (32 floats live — the only array) ----
        v2f h1[16];
        #pragma unroll
        for (int c = 0; c < 8; ++c) {
            v2f lo; lo.x = b1_0; lo.y = b1_1;
            v2f hi; hi.x = b1_2; hi.y = b1_3;
            h1[2*c]   = lo;
            h1[2*c+1] = hi;
        }
        #pragma clang loop unroll(disable)
        for (int k = 0; k < TK; ++k) {
            float4 wq = w1t[k];
            v2f w01; w01.x = wq.x; w01.y = wq.y;
            v2f w23; w23.x = wq.z; w23.y = wq.w;
            float4 xa = *(const float4*)&lds[XA_OFF + (tid + k)*4];
            float4 xc = *(const float4*)&lds[XB_OFF + (tid + k)*4];
            v2f t;
            t.x = xa.x; t.y = xa.x; h1[0]  = fma2(t, w01, h1[0]);  h1[1]  = fma2(t, w23, h1[1]);
            t.x = xa.y; t.y = xa.y; h1[2]  = fma2(t, w01, h1[2]);  h1[3]  = fma2(t, w23, h1[3]);
            t.x = xa.z; t.y = xa.z; h1[4]  = fma2(t, w01, h1[4]);  h1[5]  = fma2(t, w23, h1[5]);
            t.x = xa.w; t.y = xa.w; h1[6]  = fma2(t, w01, h1[6]);  h1[7]  = fma2(t, w23, h1[7]);
            t.x = xc.x; t.y = xc.x; h1[8]  = fma2(t, w01, h1[8]);  h1[9]  = fma2(t, w23, h1[9]);
            t.x = xc.y; t.y = xc.y; h1[10] = fma2(t, w01, h1[10]); h1[11] = fma2(t, w23, h1[11]);
            t.x = xc.z; t.y = xc.z; h1[12] = fma2(t, w01, h1[12]); h1[13] = fma2(t, w23, h1[13]);
            t.x = xc.w; t.y = xc.w; h1[14] = fma2(t, w01, h1[14]); h1[15] = fma2(t, w23, h1[15]);
        }

        // ---- conv2 partial -> accumulate into own h2 row (LDS RMW, no hazard) ----
        #pragma clang loop unroll(disable)
        for (int sb = 0; sb < 10; ++sb) {
            float vs[4];
            #pragma unroll
            for (int j = 0; j < 4; ++j) {
                int s = 4*sb + j;
                v2f a; a.x = 0.f; a.y = 0.f;
                #pragma unroll
                for (int cp = 0; cp < 8; ++cp) {
                    float4 wq = w2t[s*NCH + 8*g + cp];
                    v2f w01; w01.x = wq.x; w01.y = wq.y;
                    v2f w23; w23.x = wq.z; w23.y = wq.w;
                    a = fma2(w01, h1[2*cp],   a);
                    a = fma2(w23, h1[2*cp+1], a);
                }
                float v = a.x + a.y;
                if (g == 0) v += conv2_b[s];
                vs[j] = tvalid ? v : 0.f;
            }
            if (g == 0) {
                float4 cur;
                cur.x = vs[0]; cur.y = vs[1]; cur.z = vs[2]; cur.w = vs[3];
                *(float4*)&h2row[4*sb] = cur;
            } else {
                float4 cur = *(const float4*)&h2row[4*sb];
                cur.x += vs[0]; cur.y += vs[1]; cur.z += vs[2]; cur.w += vs[3];
                *(float4*)&h2row[4*sb] = cur;
            }
        }
    }
    __syncthreads();

    float* accb = acc + b*ACC_STRIDE;

    // ---- gram: 55 (bf<=bg) 4x4 tiles x 4 t-chunks = 220 threads ----
    if (tid < 220) {
        int tilei = tid >> 2, chunk = tid & 3;
        int bf = 0, rem = tilei;
        while (rem >= 10 - bf) { rem -= 10 - bf; bf++; }
        int bg = bf + rem;
        int tstart = chunk * 64;

        v2f accv[8];
        #pragma unroll
        for (int i = 0; i < 8; ++i) { accv[i].x = 0.f; accv[i].y = 0.f; }

        #pragma unroll 4
        for (int t = tstart; t < tstart + 64; ++t) {
            const float* row = &lds[t * H2_TSTR];
            float4 av = *(const float4*)&row[4*bf];
            float4 bv = *(const float4*)&row[4*bg];
            v2f bL; bL.x = bv.x; bL.y = bv.y;
            v2f bH; bH.x = bv.z; bH.y = bv.w;
            v2f t2;
            t2.x = av.x; t2.y = av.x; accv[0] = fma2(t2, bL, accv[0]); accv[1] = fma2(t2, bH, accv[1]);
            t2.x = av.y; t2.y = av.y; accv[2] = fma2(t2, bL, accv[2]); accv[3] = fma2(t2, bH, accv[3]);
            t2.x = av.z; t2.y = av.z; accv[4] = fma2(t2, bL, accv[4]); accv[5] = fma2(t2, bH, accv[5]);
            t2.x = av.w; t2.y = av.w; accv[6] = fma2(t2, bL, accv[6]); accv[7] = fma2(t2, bH, accv[7]);
        }
        #pragma unroll
        for (int i = 0; i < 4; ++i) {
            #pragma unroll
            for (int j = 0; j < 4; ++j) {
                if (bf != bg || i <= j) {
                    int f  = 4*bf + i;
                    int gg = 4*bg + j;
                    v2f av2 = accv[2*i + (j >> 1)];
                    float s = (j & 1) ? av2.y : av2.x;
                    atomicAdd(&accb[pack_ut(f, gg)], s);
                }
            }
        }
    }

    // ---- column sums: 40 threads in wave 3 ----
    if (tid >= 216) {
        int s = tid - 216;   // 0..39
        float cs = 0.f;
        #pragma unroll 8
        for (int t = 0; t < 256; ++t) cs += lds[t*H2_TSTR + s];
        atomicAdd(&accb[NPAIR + s], cs);
    }
}

// ---------------- K2: 1-barrier/round fused Jacobi (unchanged from R5 — passed) ----------------
__device__ __forceinline__ void pq_sched(int r, int k, int& p, int& q) {
    if (k == 0) { p = 19; q = r; }
    else {
        int a = r + k;      if (a >= 19) a -= 19;
        int d = r - k + 19; if (d >= 19) d -= 19;
        p = a; q = d;
    }
}

__device__ __forceinline__ void rotcs(float app, float aqq, float apq,
                                      float& c, float& s) {
    if (fabsf(apq) > 1e-30f) {
        float tau = (aqq - app) * __builtin_amdgcn_rcpf(2.f*apq);
        float sq  = __builtin_amdgcn_sqrtf(fmaf(tau, tau, 1.f));
        float t   = __builtin_amdgcn_rcpf(fabsf(tau) + sq);
        t = (tau < 0.f) ? -t : t;
        c = __builtin_amdgcn_rsqf(fmaf(t, t, 1.f));
        s = t * c;
    } else { c = 1.f; s = 0.f; }
}

__global__ __launch_bounds__(64)
void finalize_kernel(const float* __restrict__ acc,
                     const float* __restrict__ W_bimap,
                     const float* __restrict__ clf_w,
                     const float* __restrict__ clf_b,
                     float* __restrict__ out)
{
    __shared__ float C[NSF*NSF];
    __shared__ float Wb[NSUB*NSF];
    __shared__ float M[NSUB*NSF];
    __shared__ float A[NSUB*21];
    __shared__ float V[NSUB*21];
    __shared__ float lam[NSUB];
    __shared__ float z[NTAN];

    const int tid = threadIdx.x;
    const int b   = blockIdx.x;
    const float* accb = acc + b*ACC_STRIDE;

    for (int i = tid; i < NSF*NSF; i += 64) {
        int f = i / NSF, g = i % NSF;
        int lo = f < g ? f : g;
        int hi = f < g ? g : f;
        double G  = (double)accb[pack_ut(lo, hi)];
        double sf = (double)accb[NPAIR + f];
        double sg = (double)accb[NPAIR + g];
        C[i] = (float)((G - sf*sg*(1.0/2000.0)) * (1.0/1999.0));
    }
    for (int i = tid; i < NSUB*NSF; i += 64) Wb[i] = W_bimap[i];
    __syncthreads();

    for (int i = tid; i < NSUB*NSF; i += 64) {
        int r = i / NSF, g = i % NSF;
        float s = 0.f;
        #pragma unroll 8
        for (int f = 0; f < NSF; ++f) s = fmaf(Wb[r*NSF+f], C[f*NSF+g], s);
        M[i] = s;
    }
    __syncthreads();

    for (int i = tid; i < NSUB*NSUB; i += 64) {
        int r = i / NSUB, j = i % NSUB;
        float s = 0.f;
        #pragma unroll 8
        for (int g = 0; g < NSF; ++g) s = fmaf(M[r*NSF+g], Wb[j*NSF+g], s);
        A[r*21+j] = s;
        V[r*21+j] = (r == j) ? 1.f : 0.f;
    }
    __syncthreads();

    const int k0 = tid / 10, l0 = tid - 10*(tid/10);
    const bool has1 = (tid < 36);
    const int i1 = tid + 64;
    const int k1 = i1 / 10, l1 = i1 - 10*(i1/10);

    for (int sweep = 0; sweep < 7; ++sweep) {
        for (int r = 0; r < 19; ++r) {
            int pk0, qk0, pl0, ql0, pk1, qk1, pl1, ql1;
            pq_sched(r, k0, pk0, qk0);
            pq_sched(r, l0, pl0, ql0);
            pq_sched(r, k1, pk1, qk1);
            pq_sched(r, l1, pl1, ql1);

            float kpp0 = A[pk0*21+pk0], kqq0 = A[qk0*21+qk0], kpq0 = A[pk0*21+qk0];
            float lpp0 = A[pl0*21+pl0], lqq0 = A[ql0*21+ql0], lpq0 = A[pl0*21+ql0];
            float a00_0 = A[pk0*21+pl0], a01_0 = A[pk0*21+ql0];
            float a10_0 = A[qk0*21+pl0], a11_0 = A[qk0*21+ql0];
            float v00_0 = V[pk0*21+pl0], v01_0 = V[pk0*21+ql0];
            float v10_0 = V[qk0*21+pl0], v11_0 = V[qk0*21+ql0];

            float kpp1=0.f, kqq1=0.f, kpq1=0.f, lpp1=0.f, lqq1=0.f, lpq1=0.f;
            float a00_1=0.f, a01_1=0.f, a10_1=0.f, a11_1=0.f;
            float v00_1=0.f, v01_1=0.f, v10_1=0.f, v11_1=0.f;
            if (has1) {
                kpp1 = A[pk1*21+pk1]; kqq1 = A[qk1*21+qk1]; kpq1 = A[pk1*21+qk1];
                lpp1 = A[pl1*21+pl1]; lqq1 = A[ql1*21+ql1]; lpq1 = A[pl1*21+ql1];
                a00_1 = A[pk1*21+pl1]; a01_1 = A[pk1*21+ql1];
                a10_1 = A[qk1*21+pl1]; a11_1 = A[qk1*21+ql1];
                v00_1 = V[pk1*21+pl1]; v01_1 = V[pk1*21+ql1];
                v10_1 = V[qk1*21+pl1]; v11_1 = V[qk1*21+ql1];
            }

            float ck0, sk0, cl0, sl0, ck1, sk1, cl1, sl1;
            rotcs(kpp0, kqq0, kpq0, ck0, sk0);
            rotcs(lpp0, lqq0, lpq0, cl0, sl0);
            rotcs(kpp1, kqq1, kpq1, ck1, sk1);
            rotcs(lpp1, lqq1, lpq1, cl1, sl1);

            {
                float t00 = ck0*a00_0 - sk0*a10_0, t01 = ck0*a01_0 - sk0*a11_0;
                float t10 = sk0*a00_0 + ck0*a10_0, t11 = sk0*a01_0 + ck0*a11_0;
                A[pk0*21+pl0] = cl0*t00 - sl0*t01;
                A[pk0*21+ql0] = sl0*t00 + cl0*t01;
                A[qk0*21+pl0] = cl0*t10 - sl0*t11;
                A[qk0*21+ql0] = sl0*t10 + cl0*t11;
                V[pk0*21+pl0] = cl0*v00_0 - sl0*v01_0;
                V[pk0*21+ql0] = sl0*v00_0 + cl0*v01_0;
                V[qk0*21+pl0] = cl0*v10_0 - sl0*v11_0;
                V[qk0*21+ql0] = sl0*v10_0 + cl0*v11_0;
            }
            if (has1) {
                float t00 = ck1*a00_1 - sk1*a10_1, t01 = ck1*a01_1 - sk1*a11_1;
                float t10 = sk1*a00_1 + ck1*a10_1, t11 = sk1*a01_1 + ck1*a11_1;
                A[pk1*21+pl1] = cl1*t00 - sl1*t01;
                A[pk1*21+ql1] = sl1*t00 + cl1*t01;
                A[qk1*21+pl1] = cl1*t10 - sl1*t11;
                A[qk1*21+ql1] = sl1*t10 + cl1*t11;
                V[pk1*21+pl1] = cl1*v00_1 - sl1*v01_1;
                V[pk1*21+ql1] = sl1*v00_1 + cl1*v01_1;
                V[qk1*21+pl1] = cl1*v10_1 - sl1*v11_1;
                V[qk1*21+ql1] = sl1*v10_1 + cl1*v11_1;
            }
            __syncthreads();
        }
    }

    if (tid < NSUB) {
        float w = A[tid*21+tid];
        lam[tid] = logf(fmaxf(w, 1e-4f));
    }
    __syncthreads();

    for (int p = tid; p < NTAN; p += 64) {
        int i = 0, rem = p;
        while (rem >= NSUB - i) { rem -= NSUB - i; i++; }
        int j = i + rem;
        float s = 0.f;
        #pragma unroll 5
        for (int k = 0; k < NSUB; ++k) s = fmaf(V[i*21+k]*lam[k], V[j*21+k], s);
        z[p] = (i == j) ? s : s * 1.41421356237309515f;
    }
    __syncthreads();

    if (tid < NCLS) {
        float s = clf_b[tid];
        for (int p = 0; p < NTAN; ++p) s = fmaf(clf_w[tid*NTAN+p], z[p], s);
        out[b*NCLS + tid] = s;
    }
}

// ---------------- launch ----------------
extern "C" void kernel_launch(void* const* d_in, const int* in_sizes, int n_in,
                              void* d_out, int out_size, void* d_ws, size_t ws_size,
                              hipStream_t stream) {
    const float* x       = (const float*)d_in[0];
    const float* conv1_w = (const float*)d_in[1];
    const float* conv1_b = (const float*)d_in[2];
    const float* conv2_w = (const float*)d_in[3];
    const float* conv2_b = (const float*)d_in[4];
    const float* W_bimap = (const float*)d_in[5];
    const float* clf_w   = (const float*)d_in[6];
    const float* clf_b   = (const float*)d_in[7];
    float* out = (float*)d_out;
    float* ws  = (float*)d_ws;

    hipMemsetAsync(ws, 0, (size_t)ACC_FLOATS*sizeof(float), stream);

    prep_kernel<<<1, 256, 0, stream>>>(conv1_w, conv2_w, ws);
    conv_gram_kernel<<<B_*NTILE, 256, 0, stream>>>(x, conv1_b, conv2_b, ws, ws);
    finalize_kernel<<<B_, 64, 0, stream>>>(ws, W_bimap, clf_w, clf_b, out);
}

// Round 7
// 457.824 us; speedup vs baseline: 1.5933x; 1.5933x over previous
//
#include <hip/hip_runtime.h>
#include <math.h>

#define B_    256
#define NCH   32
#define T_    2000
#define NTF   4
#define NSF   40
#define NSUB  20
#define TK    25
#define NCLS  4
#define NTAN  210
#define NPAIR 820
#define NTILE 4            // 4 tiles x 500 t; each tile = 2 passes of 250
#define PL    12

#define W2T_OFF 0                      // 5120 floats, [s][c][f]
#define W1T_OFF 5120                   // 100 floats,  [k][f]
#define PART_OFF 5248                  // 1024 blocks x 864 floats = 3.54 MB
#define PART_STRIDE 864                // 820 gram + 40 colsum + pad

#define H2_TSTR 40          // h2[t][s]: 256 rows x 40, t-major (thread-private RMW)
#define XA_OFF  10240       // xsA[280][4] channels 8g..8g+3
#define XB_OFF  11360       // xsB[280][4] channels 8g+4..8g+7
#define LDS_DW  12480       // 49.9 KB -> 3 blocks/CU

typedef float v2f __attribute__((ext_vector_type(2)));

__device__ __forceinline__ v2f fma2(v2f a, v2f b, v2f c) {
#if __has_builtin(__builtin_elementwise_fma)
    return __builtin_elementwise_fma(a, b, c);
#else
    v2f r; r.x = fmaf(a.x, b.x, c.x); r.y = fmaf(a.y, b.y, c.y); return r;
#endif
}

__device__ __forceinline__ int pack_ut(int f, int g) {
    return f*NSF - (f*(f-1))/2 + (g - f);
}

// ---------------- K0: weight transpose ----------------
__global__ void prep_kernel(const float* __restrict__ conv1_w,
                            const float* __restrict__ conv2_w,
                            float* __restrict__ ws) {
    int tid = threadIdx.x;
    float* w2t = ws + W2T_OFF;
    float* w1t = ws + W1T_OFF;
    for (int i = tid; i < NSF*NTF*NCH; i += 256) {
        int f  = i & 3;
        int sc = i >> 2;
        int c  = sc & 31;
        int s  = sc >> 5;
        w2t[i] = conv2_w[(s*NTF + f)*NCH + c];
    }
    for (int i = tid; i < NTF*TK; i += 256) {
        int f = i & 3;
        int k = i >> 2;
        w1t[i] = conv1_w[f*TK + k];
    }
}

// ---------------- K1: fused conv1+conv2+gram, NO atomics (per-block partials) ----------------
__global__ __launch_bounds__(256, 3)
void conv_gram_kernel(const float* __restrict__ x,
                      const float* __restrict__ conv1_b,
                      const float* __restrict__ conv2_b,
                      const float* __restrict__ wts,
                      float* __restrict__ part)
{
    __shared__ float lds[LDS_DW];

    const int tid  = threadIdx.x;
    const int bid  = blockIdx.x;
    const int b    = bid >> 2;
    const int tile = bid & 3;
    const bool tvalid = (tid < 250);

    const float* xb = x + (size_t)b*NCH*T_;
    const float4* w1t = (const float4*)(wts + W1T_OFF);
    const float4* w2t = (const float4*)(wts + W2T_OFF);

    const float b1_0 = conv1_b[0], b1_1 = conv1_b[1], b1_2 = conv1_b[2], b1_3 = conv1_b[3];

    float* h2row = &lds[tid * H2_TSTR];

    // hoisted gram-tile decode (threads 0..219: 55 tiles x 4 t-chunks)
    const int tilei = tid >> 2, chunk = tid & 3;
    int bf = 0, bg = 0;
    if (tid < 220) {
        int rem = tilei;
        while (rem >= 10 - bf) { rem -= 10 - bf; bf++; }
        bg = bf + rem;
    }
    v2f accv[8];
    #pragma unroll
    for (int i = 0; i < 8; ++i) { accv[i].x = 0.f; accv[i].y = 0.f; }
    // colsum: threads 220..255 own s = tid-220 (and s+36 for tid<224)
    float cs0 = 0.f, cs1 = 0.f;
    const int scol = tid - 220;
    const bool isCol = (tid >= 220);
    const bool hasC1 = (tid >= 220 && tid < 224);

    #pragma clang loop unroll(disable)
    for (int pass = 0; pass < 2; ++pass) {
        const int t0 = tile*500 + pass*250;

        #pragma clang loop unroll(disable)
        for (int g = 0; g < 4; ++g) {
            __syncthreads();   // prior reads of xs / h2 complete
            for (int li = tid; li < 8*280; li += 256) {
                int cp = li / 280;
                int i  = li - cp*280;
                int tg = t0 + i - PL;
                tg = (tg < 0) ? -tg : tg;
                tg = (tg >= T_) ? (2*T_ - 2 - tg) : tg;
                int base = (cp < 4) ? XA_OFF : XB_OFF;
                lds[base + i*4 + (cp & 3)] = xb[(8*g + cp)*T_ + tg];
            }
            __syncthreads();

            v2f h1[16];
            #pragma unroll
            for (int c = 0; c < 8; ++c) {
                v2f lo; lo.x = b1_0; lo.y = b1_1;
                v2f hi; hi.x = b1_2; hi.y = b1_3;
                h1[2*c]   = lo;
                h1[2*c+1] = hi;
            }
            #pragma clang loop unroll(disable)
            for (int k = 0; k < TK; ++k) {
                float4 wq = w1t[k];
                v2f w01; w01.x = wq.x; w01.y = wq.y;
                v2f w23; w23.x = wq.z; w23.y = wq.w;
                float4 xa = *(const float4*)&lds[XA_OFF + (tid + k)*4];
                float4 xc = *(const float4*)&lds[XB_OFF + (tid + k)*4];
                v2f t;
                t.x = xa.x; t.y = xa.x; h1[0]  = fma2(t, w01, h1[0]);  h1[1]  = fma2(t, w23, h1[1]);
                t.x = xa.y; t.y = xa.y; h1[2]  = fma2(t, w01, h1[2]);  h1[3]  = fma2(t, w23, h1[3]);
                t.x = xa.z; t.y = xa.z; h1[4]  = fma2(t, w01, h1[4]);  h1[5]  = fma2(t, w23, h1[5]);
                t.x = xa.w; t.y = xa.w; h1[6]  = fma2(t, w01, h1[6]);  h1[7]  = fma2(t, w23, h1[7]);
                t.x = xc.x; t.y = xc.x; h1[8]  = fma2(t, w01, h1[8]);  h1[9]  = fma2(t, w23, h1[9]);
                t.x = xc.y; t.y = xc.y; h1[10] = fma2(t, w01, h1[10]); h1[11] = fma2(t, w23, h1[11]);
                t.x = xc.z; t.y = xc.z; h1[12] = fma2(t, w01, h1[12]); h1[13] = fma2(t, w23, h1[13]);
                t.x = xc.w; t.y = xc.w; h1[14] = fma2(t, w01, h1[14]); h1[15] = fma2(t, w23, h1[15]);
            }

            #pragma clang loop unroll(disable)
            for (int sb = 0; sb < 10; ++sb) {
                float vs[4];
                #pragma unroll
                for (int j = 0; j < 4; ++j) {
                    int s = 4*sb + j;
                    v2f a; a.x = 0.f; a.y = 0.f;
                    #pragma unroll
                    for (int cp = 0; cp < 8; ++cp) {
                        float4 wq = w2t[s*NCH + 8*g + cp];
                        v2f w01; w01.x = wq.x; w01.y = wq.y;
                        v2f w23; w23.x = wq.z; w23.y = wq.w;
                        a = fma2(w01, h1[2*cp],   a);
                        a = fma2(w23, h1[2*cp+1], a);
                    }
                    float v = a.x + a.y;
                    if (g == 0) v += conv2_b[s];
                    vs[j] = tvalid ? v : 0.f;
                }
                if (g == 0) {
                    float4 cur;
                    cur.x = vs[0]; cur.y = vs[1]; cur.z = vs[2]; cur.w = vs[3];
                    *(float4*)&h2row[4*sb] = cur;
                } else {
                    float4 cur = *(const float4*)&h2row[4*sb];
                    cur.x += vs[0]; cur.y += vs[1]; cur.z += vs[2]; cur.w += vs[3];
                    *(float4*)&h2row[4*sb] = cur;
                }
            }
        }
        __syncthreads();   // h2 complete for this pass

        // ---- gram accumulate (persistent regs across passes) ----
        if (tid < 220) {
            const int tstart = chunk * 64;
            #pragma unroll 4
            for (int t = tstart; t < tstart + 64; ++t) {
                const float* row = &lds[t * H2_TSTR];
                float4 av = *(const float4*)&row[4*bf];
                float4 bv = *(const float4*)&row[4*bg];
                v2f bL; bL.x = bv.x; bL.y = bv.y;
                v2f bH; bH.x = bv.z; bH.y = bv.w;
                v2f t2;
                t2.x = av.x; t2.y = av.x; accv[0] = fma2(t2, bL, accv[0]); accv[1] = fma2(t2, bH, accv[1]);
                t2.x = av.y; t2.y = av.y; accv[2] = fma2(t2, bL, accv[2]); accv[3] = fma2(t2, bH, accv[3]);
                t2.x = av.z; t2.y = av.z; accv[4] = fma2(t2, bL, accv[4]); accv[5] = fma2(t2, bH, accv[5]);
                t2.x = av.w; t2.y = av.w; accv[6] = fma2(t2, bL, accv[6]); accv[7] = fma2(t2, bH, accv[7]);
            }
        } else {
            #pragma unroll 8
            for (int t = 0; t < 256; ++t) cs0 += lds[t*H2_TSTR + scol];
            if (hasC1) {
                #pragma unroll 8
                for (int t = 0; t < 256; ++t) cs1 += lds[t*H2_TSTR + scol + 36];
            }
        }
    }
    __syncthreads();   // all h2 reads done; lds reusable for partial staging

    float* pb = part + (size_t)bid * PART_STRIDE;

    // ---- stage gram partials: lds[tilei*64 + e*4 + chunk] ----
    if (tid < 220) {
        #pragma unroll
        for (int i = 0; i < 4; ++i) {
            #pragma unroll
            for (int j = 0; j < 4; ++j) {
                v2f av2 = accv[2*i + (j >> 1)];
                float v = (j & 1) ? av2.y : av2.x;
                lds[tilei*64 + (i*4 + j)*4 + chunk] = v;
            }
        }
    }
    if (isCol) {
        pb[NPAIR + scol] = cs0;
        if (hasC1) pb[NPAIR + scol + 36] = cs1;
    }
    __syncthreads();

    // ---- reduce 4 chunks and store 820 gram entries (no atomics) ----
    for (int slot = tid; slot < 880; slot += 256) {
        int ti = slot >> 4, e = slot & 15;
        int i = e >> 2, j = e & 3;
        int tbf = 0, rem = ti;
        while (rem >= 10 - tbf) { rem -= 10 - tbf; tbf++; }
        int tbg = tbf + rem;
        if (tbf != tbg || i <= j) {
            float s = lds[ti*64 + e*4 + 0] + lds[ti*64 + e*4 + 1]
                    + lds[ti*64 + e*4 + 2] + lds[ti*64 + e*4 + 3];
            int f  = 4*tbf + i;
            int gg = 4*tbg + j;
            pb[pack_ut(f, gg)] = s;
        }
    }
}

// ---------------- K2: gather partials -> cov -> bimap -> Jacobi -> log -> head ----------------
__device__ __forceinline__ void pq_sched(int r, int k, int& p, int& q) {
    if (k == 0) { p = 19; q = r; }
    else {
        int a = r + k;      if (a >= 19) a -= 19;
        int d = r - k + 19; if (d >= 19) d -= 19;
        p = a; q = d;
    }
}

__device__ __forceinline__ void rotcs(float app, float aqq, float apq,
                                      float& c, float& s) {
    if (fabsf(apq) > 1e-30f) {
        float tau = (aqq - app) * __builtin_amdgcn_rcpf(2.f*apq);
        float sq  = __builtin_amdgcn_sqrtf(fmaf(tau, tau, 1.f));
        float t   = __builtin_amdgcn_rcpf(fabsf(tau) + sq);
        t = (tau < 0.f) ? -t : t;
        c = __builtin_amdgcn_rsqf(fmaf(t, t, 1.f));
        s = t * c;
    } else { c = 1.f; s = 0.f; }
}

__global__ __launch_bounds__(64)
void finalize_kernel(const float* __restrict__ part,
                     const float* __restrict__ W_bimap,
                     const float* __restrict__ clf_w,
                     const float* __restrict__ clf_b,
                     float* __restrict__ out)
{
    __shared__ float Gacc[PART_STRIDE];
    __shared__ float C[NSF*NSF];
    __shared__ float Wb[NSUB*NSF];
    __shared__ float M[NSUB*NSF];
    __shared__ float A[NSUB*21];
    __shared__ float V[NSUB*21];
    __shared__ float lam[NSUB];
    __shared__ float z[NTAN];

    const int tid = threadIdx.x;
    const int b   = blockIdx.x;

    // gather the 4 per-tile partials
    for (int i = tid; i < NPAIR + NSF; i += 64) {
        double s = 0.0;
        #pragma unroll
        for (int t = 0; t < 4; ++t)
            s += (double)part[(size_t)(b*4 + t)*PART_STRIDE + i];
        Gacc[i] = (float)s;
    }
    for (int i = tid; i < NSUB*NSF; i += 64) Wb[i] = W_bimap[i];
    __syncthreads();

    for (int i = tid; i < NSF*NSF; i += 64) {
        int f = i / NSF, g = i % NSF;
        int lo = f < g ? f : g;
        int hi = f < g ? g : f;
        double G  = (double)Gacc[pack_ut(lo, hi)];
        double sf = (double)Gacc[NPAIR + f];
        double sg = (double)Gacc[NPAIR + g];
        C[i] = (float)((G - sf*sg*(1.0/2000.0)) * (1.0/1999.0));
    }
    __syncthreads();

    for (int i = tid; i < NSUB*NSF; i += 64) {
        int r = i / NSF, g = i % NSF;
        float s = 0.f;
        #pragma unroll 8
        for (int f = 0; f < NSF; ++f) s = fmaf(Wb[r*NSF+f], C[f*NSF+g], s);
        M[i] = s;
    }
    __syncthreads();

    for (int i = tid; i < NSUB*NSUB; i += 64) {
        int r = i / NSUB, j = i % NSUB;
        float s = 0.f;
        #pragma unroll 8
        for (int g = 0; g < NSF; ++g) s = fmaf(M[r*NSF+g], Wb[j*NSF+g], s);
        A[r*21+j] = s;
        V[r*21+j] = (r == j) ? 1.f : 0.f;
    }
    __syncthreads();

    const int k0 = tid / 10, l0 = tid - 10*(tid/10);
    const bool has1 = (tid < 36);
    const int i1 = tid + 64;
    const int k1 = i1 / 10, l1 = i1 - 10*(i1/10);

    for (int sweep = 0; sweep < 6; ++sweep) {
        for (int r = 0; r < 19; ++r) {
            int pk0, qk0, pl0, ql0, pk1, qk1, pl1, ql1;
            pq_sched(r, k0, pk0, qk0);
            pq_sched(r, l0, pl0, ql0);
            pq_sched(r, k1, pk1, qk1);
            pq_sched(r, l1, pl1, ql1);

            float kpp0 = A[pk0*21+pk0], kqq0 = A[qk0*21+qk0], kpq0 = A[pk0*21+qk0];
            float lpp0 = A[pl0*21+pl0], lqq0 = A[ql0*21+ql0], lpq0 = A[pl0*21+ql0];
            float a00_0 = A[pk0*21+pl0], a01_0 = A[pk0*21+ql0];
            float a10_0 = A[qk0*21+pl0], a11_0 = A[qk0*21+ql0];
            float v00_0 = V[pk0*21+pl0], v01_0 = V[pk0*21+ql0];
            float v10_0 = V[qk0*21+pl0], v11_0 = V[qk0*21+ql0];

            float kpp1=0.f, kqq1=0.f, kpq1=0.f, lpp1=0.f, lqq1=0.f, lpq1=0.f;
            float a00_1=0.f, a01_1=0.f, a10_1=0.f, a11_1=0.f;
            float v00_1=0.f, v01_1=0.f, v10_1=0.f, v11_1=0.f;
            if (has1) {
                kpp1 = A[pk1*21+pk1]; kqq1 = A[qk1*21+qk1]; kpq1 = A[pk1*21+qk1];
                lpp1 = A[pl1*21+pl1]; lqq1 = A[ql1*21+ql1]; lpq1 = A[pl1*21+ql1];
                a00_1 = A[pk1*21+pl1]; a01_1 = A[pk1*21+ql1];
                a10_1 = A[qk1*21+pl1]; a11_1 = A[qk1*21+ql1];
                v00_1 = V[pk1*21+pl1]; v01_1 = V[pk1*21+ql1];
                v10_1 = V[qk1*21+pl1]; v11_1 = V[qk1*21+ql1];
            }

            float ck0, sk0, cl0, sl0, ck1, sk1, cl1, sl1;
            rotcs(kpp0, kqq0, kpq0, ck0, sk0);
            rotcs(lpp0, lqq0, lpq0, cl0, sl0);
            rotcs(kpp1, kqq1, kpq1, ck1, sk1);
            rotcs(lpp1, lqq1, lpq1, cl1, sl1);

            {
                float t00 = ck0*a00_0 - sk0*a10_0, t01 = ck0*a01_0 - sk0*a11_0;
                float t10 = sk0*a00_0 + ck0*a10_0, t11 = sk0*a01_0 + ck0*a11_0;
                A[pk0*21+pl0] = cl0*t00 - sl0*t01;
                A[pk0*21+ql0] = sl0*t00 + cl0*t01;
                A[qk0*21+pl0] = cl0*t10 - sl0*t11;
                A[qk0*21+ql0] = sl0*t10 + cl0*t11;
                V[pk0*21+pl0] = cl0*v00_0 - sl0*v01_0;
                V[pk0*21+ql0] = sl0*v00_0 + cl0*v01_0;
                V[qk0*21+pl0] = cl0*v10_0 - sl0*v11_0;
                V[qk0*21+ql0] = sl0*v10_0 + cl0*v11_0;
            }
            if (has1) {
                float t00 = ck1*a00_1 - sk1*a10_1, t01 = ck1*a01_1 - sk1*a11_1;
                float t10 = sk1*a00_1 + ck1*a10_1, t11 = sk1*a01_1 + ck1*a11_1;
                A[pk1*21+pl1] = cl1*t00 - sl1*t01;
                A[pk1*21+ql1] = sl1*t00 + cl1*t01;
                A[qk1*21+pl1] = cl1*t10 - sl1*t11;
                A[qk1*21+ql1] = sl1*t10 + cl1*t11;
                V[pk1*21+pl1] = cl1*v00_1 - sl1*v01_1;
                V[pk1*21+ql1] = sl1*v00_1 + cl1*v01_1;
                V[qk1*21+pl1] = cl1*v10_1 - sl1*v11_1;
                V[qk1*21+ql1] = sl1*v10_1 + cl1*v11_1;
            }
            __syncthreads();
        }
    }

    if (tid < NSUB) {
        float w = A[tid*21+tid];
        lam[tid] = logf(fmaxf(w, 1e-4f));
    }
    __syncthreads();

    for (int p = tid; p < NTAN; p += 64) {
        int i = 0, rem = p;
        while (rem >= NSUB - i) { rem -= NSUB - i; i++; }
        int j = i + rem;
        float s = 0.f;
        #pragma unroll 5
        for (int k = 0; k < NSUB; ++k) s = fmaf(V[i*21+k]*lam[k], V[j*21+k], s);
        z[p] = (i == j) ? s : s * 1.41421356237309515f;
    }
    __syncthreads();

    if (tid < NCLS) {
        float s = clf_b[tid];
        for (int p = 0; p < NTAN; ++p) s = fmaf(clf_w[tid*NTAN+p], z[p], s);
        out[b*NCLS + tid] = s;
    }
}

// ---------------- launch ----------------
extern "C" void kernel_launch(void* const* d_in, const int* in_sizes, int n_in,
                              void* d_out, int out_size, void* d_ws, size_t ws_size,
                              hipStream_t stream) {
    const float* x       = (const float*)d_in[0];
    const float* conv1_w = (const float*)d_in[1];
    const float* conv1_b = (const float*)d_in[2];
    const float* conv2_w = (const float*)d_in[3];
    const float* conv2_b = (const float*)d_in[4];
    const float* W_bimap = (const float*)d_in[5];
    const float* clf_w   = (const float*)d_in[6];
    const float* clf_b   = (const float*)d_in[7];
    float* out = (float*)d_out;
    float* ws  = (float*)d_ws;

    prep_kernel<<<1, 256, 0, stream>>>(conv1_w, conv2_w, ws);
    conv_gram_kernel<<<B_*NTILE, 256, 0, stream>>>(x, conv1_b, conv2_b, ws, ws + PART_OFF);
    finalize_kernel<<<B_, 64, 0, stream>>>(ws + PART_OFF, W_bimap, clf_w, clf_b, out);
}

// Round 8
// 422.973 us; speedup vs baseline: 1.7246x; 1.0824x over previous
//
#include <hip/hip_runtime.h>
#include <math.h>

#define B_    256
#define NCH   32
#define T_    2000
#define NTF   4
#define NSF   40
#define NSUB  20
#define TK    25
#define NCLS  4
#define NTAN  210
#define NPAIR 820
#define PL    12

#define W2T_OFF 0                      // 5120 floats, [s][c][f]
#define W1T_OFF 5120                   // 100 floats,  [k][f]
#define PART_OFF 5248
#define PART_STRIDE 864                // 820 gram + 40 colsum + pad

#define XS_TSTR 36                     // xs[t][c]: 280 x 36 dwords
#define H2_STR  260                    // h2[s][t]: 40 x 260 (250 data + 10 zero)
#define LDS_DW  10400                  // 41.6 KB -> 3 blocks/CU

typedef float v2f __attribute__((ext_vector_type(2)));

__device__ __forceinline__ v2f fma2(v2f a, v2f b, v2f c) {
#if __has_builtin(__builtin_elementwise_fma)
    return __builtin_elementwise_fma(a, b, c);
#else
    v2f r; r.x = fmaf(a.x, b.x, c.x); r.y = fmaf(a.y, b.y, c.y); return r;
#endif
}

__device__ __forceinline__ int pack_ut(int f, int g) {
    return f*NSF - (f*(f-1))/2 + (g - f);
}

// ---------------- K0: weight transpose ----------------
__global__ void prep_kernel(const float* __restrict__ conv1_w,
                            const float* __restrict__ conv2_w,
                            float* __restrict__ ws) {
    int tid = threadIdx.x;
    float* w2t = ws + W2T_OFF;
    float* w1t = ws + W1T_OFF;
    for (int i = tid; i < NSF*NTF*NCH; i += 256) {
        int f  = i & 3;
        int sc = i >> 2;
        int c  = sc & 31;
        int s  = sc >> 5;
        w2t[i] = conv2_w[(s*NTF + f)*NCH + c];
    }
    for (int i = tid; i < NTF*TK; i += 256) {
        int f = i & 3;
        int k = i >> 2;
        w1t[i] = conv1_w[f*TK + k];
    }
}

// ---------------- K1: R3 conv/gram structure + non-atomic partials ----------------
__global__ __launch_bounds__(256, 2)
void conv_gram_kernel(const float* __restrict__ x,
                      const float* __restrict__ conv1_b,
                      const float* __restrict__ conv2_b,
                      const float* __restrict__ wts,
                      float* __restrict__ part)
{
    __shared__ float lds[LDS_DW];   // union: xs[280][36] then h2[40][260]

    const int tid   = threadIdx.x;
    const int bid   = blockIdx.x;
    const int ntile = gridDim.x >> 8;            // 8 or 4
    const int sh    = (ntile == 8) ? 3 : 2;
    const int b     = bid >> sh;
    const int tile  = bid & (ntile - 1);
    const int npass = (ntile == 8) ? 1 : 2;

    const float* xb = x + (size_t)b*NCH*T_;
    const float4* w1t = (const float4*)(wts + W1T_OFF);
    const float4* w2t = (const float4*)(wts + W2T_OFF);

    // gram tile decode: 210 tiles (bf<=bg over 20 pair-blocks)
    int bf = 0, bg = 0;
    if (tid < 210) {
        int rem = tid;
        while (rem >= NSUB - bf) { rem -= NSUB - bf; bf++; }
        bg = bf + rem;
    }
    float4 e00 = make_float4(0,0,0,0), e01 = e00, e10 = e00, e11 = e00;
    float csum = 0.f;
    const int scol = tid - 216;                  // colsum threads 216..255
    const bool isCol = (tid >= 216);

    #pragma clang loop unroll(disable)
    for (int pass = 0; pass < npass; ++pass) {
        const int t0 = (tile*npass + pass) * 250;
        __syncthreads();   // prior h2 reads (pass>0) complete

        // ---- stage x transposed: xs[i][c] at lds[i*36+c] ----
        for (int li = tid; li < NCH*280; li += 256) {
            int c = li / 280;
            int i = li - c*280;
            int tg = t0 + i - PL;
            tg = (tg < 0) ? -tg : tg;
            tg = (tg >= T_) ? (2*T_ - 2 - tg) : tg;
            lds[i*XS_TSTR + c] = xb[c*T_ + tg];
        }
        __syncthreads();

        // ---- conv1: h1[c][f] as v2f pairs; per k read 32 ch as 8 b128 ----
        v2f h1[64];
        {
            float b0 = conv1_b[0], b1 = conv1_b[1], b2 = conv1_b[2], b3 = conv1_b[3];
            #pragma unroll
            for (int c = 0; c < NCH; ++c) {
                v2f lo; lo.x = b0; lo.y = b1;
                v2f hi; hi.x = b2; hi.y = b3;
                h1[2*c]   = lo;
                h1[2*c+1] = hi;
            }
        }
        #pragma clang loop unroll(disable)
        for (int k = 0; k < TK; ++k) {
            float4 wq = w1t[k];
            v2f w01; w01.x = wq.x; w01.y = wq.y;
            v2f w23; w23.x = wq.z; w23.y = wq.w;
            const float4* xr = (const float4*)&lds[(tid + k)*XS_TSTR];
            float4 xv4[8];
            #pragma unroll
            for (int j = 0; j < 8; ++j) xv4[j] = xr[j];
            #pragma unroll
            for (int j = 0; j < 8; ++j) {
                float4 xq = xv4[j];
                v2f t;
                t.x = xq.x; t.y = xq.x; h1[8*j+0] = fma2(t, w01, h1[8*j+0]); h1[8*j+1] = fma2(t, w23, h1[8*j+1]);
                t.x = xq.y; t.y = xq.y; h1[8*j+2] = fma2(t, w01, h1[8*j+2]); h1[8*j+3] = fma2(t, w23, h1[8*j+3]);
                t.x = xq.z; t.y = xq.z; h1[8*j+4] = fma2(t, w01, h1[8*j+4]); h1[8*j+5] = fma2(t, w23, h1[8*j+5]);
                t.x = xq.w; t.y = xq.w; h1[8*j+6] = fma2(t, w01, h1[8*j+6]); h1[8*j+7] = fma2(t, w23, h1[8*j+7]);
            }
        }
        __syncthreads();   // xs dead; lds becomes h2

        // ---- conv2: s rolled (x2); write h2[s][t] rows once ----
        #pragma clang loop unroll_count(2)
        for (int s = 0; s < NSF; ++s) {
            v2f a01; a01.x = conv2_b[s]; a01.y = 0.f;
            v2f a23; a23.x = 0.f;        a23.y = 0.f;
            #pragma unroll
            for (int c = 0; c < NCH; ++c) {
                float4 wq = w2t[s*NCH + c];
                v2f w01; w01.x = wq.x; w01.y = wq.y;
                v2f w23; w23.x = wq.z; w23.y = wq.w;
                a01 = fma2(w01, h1[2*c],   a01);
                a23 = fma2(w23, h1[2*c+1], a23);
            }
            float v = (a01.x + a01.y) + (a23.x + a23.y);
            lds[s*H2_STR + tid] = (tid < 250) ? v : 0.f;
        }
        for (int i = tid; i < NSF*4; i += 256) {     // cols 256..259
            int s = i >> 2;
            lds[s*H2_STR + 256 + (i & 3)] = 0.f;
        }
        __syncthreads();

        // ---- gram accumulate: 2x2 pair-block tiles, full rows b128 ----
        if (tid < 210) {
            const float4* r0 = (const float4*)&lds[(2*bf  )*H2_STR];
            const float4* r1 = (const float4*)&lds[(2*bf+1)*H2_STR];
            const float4* r2 = (const float4*)&lds[(2*bg  )*H2_STR];
            const float4* r3 = (const float4*)&lds[(2*bg+1)*H2_STR];
            #pragma unroll 5
            for (int q = 0; q < H2_STR/4; ++q) {
                float4 a0 = r0[q], a1 = r1[q], b0 = r2[q], b1 = r3[q];
                e00.x = fmaf(a0.x, b0.x, e00.x); e00.y = fmaf(a0.y, b0.y, e00.y);
                e00.z = fmaf(a0.z, b0.z, e00.z); e00.w = fmaf(a0.w, b0.w, e00.w);
                e01.x = fmaf(a0.x, b1.x, e01.x); e01.y = fmaf(a0.y, b1.y, e01.y);
                e01.z = fmaf(a0.z, b1.z, e01.z); e01.w = fmaf(a0.w, b1.w, e01.w);
                e10.x = fmaf(a1.x, b0.x, e10.x); e10.y = fmaf(a1.y, b0.y, e10.y);
                e10.z = fmaf(a1.z, b0.z, e10.z); e10.w = fmaf(a1.w, b0.w, e10.w);
                e11.x = fmaf(a1.x, b1.x, e11.x); e11.y = fmaf(a1.y, b1.y, e11.y);
                e11.z = fmaf(a1.z, b1.z, e11.z); e11.w = fmaf(a1.w, b1.w, e11.w);
            }
        }
        if (isCol) {
            const float4* rr = (const float4*)&lds[scol*H2_STR];
            #pragma unroll 5
            for (int q = 0; q < H2_STR/4; ++q) {
                float4 v = rr[q];
                csum += (v.x + v.y) + (v.z + v.w);
            }
        }
    }

    // ---- write partials, NO atomics ----
    float* pb = part + (size_t)bid * PART_STRIDE;
    if (tid < 210) {
        int f0 = 2*bf, f1 = 2*bf+1, g0 = 2*bg, g1 = 2*bg+1;
        float s00 = (e00.x+e00.y)+(e00.z+e00.w);
        float s01 = (e01.x+e01.y)+(e01.z+e01.w);
        float s10 = (e10.x+e10.y)+(e10.z+e10.w);
        float s11 = (e11.x+e11.y)+(e11.z+e11.w);
        pb[pack_ut(f0,g0)] = s00;
        pb[pack_ut(f0,g1)] = s01;
        if (bf != bg) pb[pack_ut(f1,g0)] = s10;
        pb[pack_ut(f1,g1)] = s11;
    }
    if (isCol) pb[NPAIR + scol] = csum;
}

// ---------------- K2: table-driven Jacobi, 1 rotation compute + shfl broadcast ----------------
__device__ __forceinline__ void pq_sched(int r, int k, int& p, int& q) {
    if (k == 0) { p = 19; q = r; }
    else {
        int a = r + k;      if (a >= 19) a -= 19;
        int d = r - k + 19; if (d >= 19) d -= 19;
        p = a; q = d;
    }
}

__device__ __forceinline__ void rotcs(float app, float aqq, float apq,
                                      float& c, float& s) {
    if (fabsf(apq) > 1e-30f) {
        float tau = (aqq - app) * __builtin_amdgcn_rcpf(2.f*apq);
        float sq  = __builtin_amdgcn_sqrtf(fmaf(tau, tau, 1.f));
        float t   = __builtin_amdgcn_rcpf(fabsf(tau) + sq);
        t = (tau < 0.f) ? -t : t;
        c = __builtin_amdgcn_rsqf(fmaf(t, t, 1.f));
        s = t * c;
    } else { c = 1.f; s = 0.f; }
}

__global__ __launch_bounds__(64)
void finalize_kernel(const float* __restrict__ part,
                     const float* __restrict__ W_bimap,
                     const float* __restrict__ clf_w,
                     const float* __restrict__ clf_b,
                     float* __restrict__ out,
                     int ntile)
{
    __shared__ float Gacc[PART_STRIDE];
    __shared__ float C[NSF*NSF];
    __shared__ float Wb[NSUB*NSF];
    __shared__ float M[NSUB*NSF];
    __shared__ float A[NSUB*21];
    __shared__ float V[NSUB*21];
    __shared__ float lam[NSUB];
    __shared__ float z[NTAN];
    __shared__ int4 tab0[19*64];
    __shared__ int4 tab1[19*36];
    __shared__ int4 tabR[19*10];

    const int tid = threadIdx.x;
    const int b   = blockIdx.x;

    // gather partials
    for (int i = tid; i < NPAIR + NSF; i += 64) {
        double s = 0.0;
        for (int t = 0; t < ntile; ++t)
            s += (double)part[(size_t)(b*ntile + t)*PART_STRIDE + i];
        Gacc[i] = (float)s;
    }
    for (int i = tid; i < NSUB*NSF; i += 64) Wb[i] = W_bimap[i];

    // precompute offset tables (reused across all sweeps)
    for (int i = tid; i < 19*64; i += 64) {
        int r = i >> 6, it = i & 63;
        int k = it / 10, l = it - 10*k;
        int pk, qk, pl, ql;
        pq_sched(r, k, pk, qk);
        pq_sched(r, l, pl, ql);
        tab0[i] = make_int4(pk*21+pl, pk*21+ql, qk*21+pl, qk*21+ql);
    }
    for (int i = tid; i < 19*36; i += 64) {
        int r = i / 36, t = i - 36*r;
        int it = t + 64;
        int k = it / 10, l = it - 10*k;
        int pk, qk, pl, ql;
        pq_sched(r, k, pk, qk);
        pq_sched(r, l, pl, ql);
        tab1[i] = make_int4(pk*21+pl, pk*21+ql, qk*21+pl, qk*21+ql);
    }
    for (int i = tid; i < 19*10; i += 64) {
        int r = i / 10, k = i - 10*r;
        int p, q;
        pq_sched(r, k, p, q);
        tabR[i] = make_int4(p*21+p, q*21+q, p*21+q, 0);
    }
    __syncthreads();

    for (int i = tid; i < NSF*NSF; i += 64) {
        int f = i / NSF, g = i % NSF;
        int lo = f < g ? f : g;
        int hi = f < g ? g : f;
        double G  = (double)Gacc[pack_ut(lo, hi)];
        double sf = (double)Gacc[NPAIR + f];
        double sg = (double)Gacc[NPAIR + g];
        C[i] = (float)((G - sf*sg*(1.0/2000.0)) * (1.0/1999.0));
    }
    __syncthreads();

    for (int i = tid; i < NSUB*NSF; i += 64) {
        int r = i / NSF, g = i % NSF;
        float s = 0.f;
        #pragma unroll 8
        for (int f = 0; f < NSF; ++f) s = fmaf(Wb[r*NSF+f], C[f*NSF+g], s);
        M[i] = s;
    }
    __syncthreads();

    for (int i = tid; i < NSUB*NSUB; i += 64) {
        int r = i / NSUB, j = i % NSUB;
        float s = 0.f;
        #pragma unroll 8
        for (int g = 0; g < NSF; ++g) s = fmaf(M[r*NSF+g], Wb[j*NSF+g], s);
        A[r*21+j] = s;
        V[r*21+j] = (r == j) ? 1.f : 0.f;
    }
    __syncthreads();

    const int m0 = tid - 10*(tid/10);   // tid % 10: this lane computes rotation for pair m0
    const int k0 = tid / 10;            // item0 = (k0, m0)
    const bool has1 = (tid < 36);
    const int it1 = tid + 64;
    const int k1 = it1 / 10, l1 = it1 - 10*(it1/10);

    for (int sweep = 0; sweep < 6; ++sweep) {
        for (int r = 0; r < 19; ++r) {
            // every lane computes the rotation for pair m0 (lanes with same m0 agree)
            int4 ro = tabR[r*10 + m0];
            float app = A[ro.x], aqq = A[ro.y], apq = A[ro.z];
            float c, s;
            rotcs(app, aqq, apq, c, s);
            // broadcast: (cl0,sl0) = own; others via shfl
            float cl0 = c, sl0 = s;
            float ck0 = __shfl(c, k0), sk0 = __shfl(s, k0);
            float ck1 = __shfl(c, k1), sk1 = __shfl(s, k1);
            float cl1 = __shfl(c, l1), sl1 = __shfl(s, l1);

            int4 o0 = tab0[r*64 + tid];
            float a00 = A[o0.x], a01 = A[o0.y], a10 = A[o0.z], a11 = A[o0.w];
            float v00 = V[o0.x], v01 = V[o0.y], v10 = V[o0.z], v11 = V[o0.w];

            int4 o1 = tab1[r*36 + (has1 ? tid : 0)];
            float b00=0.f, b01=0.f, b10=0.f, b11=0.f;
            float w00=0.f, w01v=0.f, w10=0.f, w11=0.f;
            if (has1) {
                b00 = A[o1.x]; b01 = A[o1.y]; b10 = A[o1.z]; b11 = A[o1.w];
                w00 = V[o1.x]; w01v = V[o1.y]; w10 = V[o1.z]; w11 = V[o1.w];
            }

            {
                float t00 = ck0*a00 - sk0*a10, t01 = ck0*a01 - sk0*a11;
                float t10 = sk0*a00 + ck0*a10, t11 = sk0*a01 + ck0*a11;
                A[o0.x] = cl0*t00 - sl0*t01;
                A[o0.y] = sl0*t00 + cl0*t01;
                A[o0.z] = cl0*t10 - sl0*t11;
                A[o0.w] = sl0*t10 + cl0*t11;
                V[o0.x] = cl0*v00 - sl0*v01;
                V[o0.y] = sl0*v00 + cl0*v01;
                V[o0.z] = cl0*v10 - sl0*v11;
                V[o0.w] = sl0*v10 + cl0*v11;
            }
            if (has1) {
                float t00 = ck1*b00 - sk1*b10, t01 = ck1*b01 - sk1*b11;
                float t10 = sk1*b00 + ck1*b10, t11 = sk1*b01 + ck1*b11;
                A[o1.x] = cl1*t00 - sl1*t01;
                A[o1.y] = sl1*t00 + cl1*t01;
                A[o1.z] = cl1*t10 - sl1*t11;
                A[o1.w] = sl1*t10 + cl1*t11;
                V[o1.x] = cl1*w00 - sl1*w01v;
                V[o1.y] = sl1*w00 + cl1*w01v;
                V[o1.z] = cl1*w10 - sl1*w11;
                V[o1.w] = sl1*w10 + cl1*w11;
            }
            __syncthreads();
        }
    }

    if (tid < NSUB) {
        float w = A[tid*21+tid];
        lam[tid] = logf(fmaxf(w, 1e-4f));
    }
    __syncthreads();

    for (int p = tid; p < NTAN; p += 64) {
        int i = 0, rem = p;
        while (rem >= NSUB - i) { rem -= NSUB - i; i++; }
        int j = i + rem;
        float s = 0.f;
        #pragma unroll 5
        for (int k = 0; k < NSUB; ++k) s = fmaf(V[i*21+k]*lam[k], V[j*21+k], s);
        z[p] = (i == j) ? s : s * 1.41421356237309515f;
    }
    __syncthreads();

    if (tid < NCLS) {
        float s = clf_b[tid];
        for (int p = 0; p < NTAN; ++p) s = fmaf(clf_w[tid*NTAN+p], z[p], s);
        out[b*NCLS + tid] = s;
    }
}

// ---------------- launch ----------------
extern "C" void kernel_launch(void* const* d_in, const int* in_sizes, int n_in,
                              void* d_out, int out_size, void* d_ws, size_t ws_size,
                              hipStream_t stream) {
    const float* x       = (const float*)d_in[0];
    const float* conv1_w = (const float*)d_in[1];
    const float* conv1_b = (const float*)d_in[2];
    const float* conv2_w = (const float*)d_in[3];
    const float* conv2_b = (const float*)d_in[4];
    const float* W_bimap = (const float*)d_in[5];
    const float* clf_w   = (const float*)d_in[6];
    const float* clf_b   = (const float*)d_in[7];
    float* out = (float*)d_out;
    float* ws  = (float*)d_ws;

    const size_t need8 = (size_t)(PART_OFF + 2048*PART_STRIDE) * sizeof(float);
    const int ntile = (ws_size >= need8) ? 8 : 4;

    prep_kernel<<<1, 256, 0, stream>>>(conv1_w, conv2_w, ws);
    conv_gram_kernel<<<B_*ntile, 256, 0, stream>>>(x, conv1_b, conv2_b, ws, ws + PART_OFF);
    finalize_kernel<<<B_, 64, 0, stream>>>(ws + PART_OFF, W_bimap, clf_w, clf_b, out, ntile);
}